// Round 3
// baseline (102.863 us; speedup 1.0000x reference)
//
#include <hip/hip_runtime.h>

// Problem constants (match the reference file).
constexpr int DIM = 512;   // irreps dim for x, y, out
constexpr int C   = 16;    // channel multiplicity
constexpr int TPB = 1024;  // threads per block (16 waves)

// LDS float-index swizzle for row a, channel-quad c4 (multiples of 4):
//   fidx = (a<<4) ^ ((a&7)<<2) ^ c4
// XORs row bits into bits [4:2] of the float index -> each row's four 16B
// chunks scatter bijectively across a 128B bank window (all 32 banks used).
__device__ __forceinline__ int swz_base(int a) { return (a << 4) ^ ((a & 7) << 2); }

// One setup kernel: pack per-path data AND compute segment starts.
// pdata[p] = {swizzled x-row base, swizzled y-row base, scale bits, 0}
// start[d] = first p with index_out[p] >= d (index_out sorted); start[DIM]=nnz.
__global__ void setup_kernel(const int* __restrict__ io,
                             const int* __restrict__ i1,
                             const int* __restrict__ i2,
                             const float* __restrict__ scale,
                             int* __restrict__ start,
                             int4* __restrict__ pdata,
                             int nnz) {
    int t = blockIdx.x * blockDim.x + threadIdx.x;
    if (t < nnz) {
        int a = i1[t], b = i2[t];
        pdata[t] = make_int4(swz_base(a), swz_base(b), __float_as_int(scale[t]), 0);
    }
    if (t <= DIM) {
        int lo = 0, hi = nnz;
        while (lo < hi) {
            int mid = (lo + hi) >> 1;
            if (io[mid] < t) lo = mid + 1; else hi = mid;
        }
        start[t] = lo;
    }
}

// One block per n. Stage x-row and y-row in LDS (XOR-swizzled layout), then
// each thread owns (d, c-quad) and walks the sorted segment for d with a
// 1-deep software pipeline. No atomics; every output written exactly once.
__global__ __launch_bounds__(TPB) void tp_lds_kernel(
    const float* __restrict__ x, const float* __restrict__ y,
    const int* __restrict__ start,
    const int4* __restrict__ pdata,
    float* __restrict__ out) {
    __shared__ float xs[DIM * C];   // 32 KiB
    __shared__ float ys[DIM * C];   // 32 KiB  -> 64 KiB total, 2 blocks/CU

    const int n = blockIdx.x;
    const float4* __restrict__ xr = reinterpret_cast<const float4*>(x + (size_t)n * (DIM * C));
    const float4* __restrict__ yr = reinterpret_cast<const float4*>(y + (size_t)n * (DIM * C));
    float4* xs4 = reinterpret_cast<float4*>(xs);
    float4* ys4 = reinterpret_cast<float4*>(ys);

    // Coalesced staging into the swizzled layout. Slot i holds row a=i>>2,
    // chunk cq=i&3; swizzled float4-slot = (a<<2) ^ (a&7) ^ cq.
    #pragma unroll
    for (int i = threadIdx.x; i < DIM * C / 4; i += TPB) {
        const int a = i >> 2, cq = i & 3;
        const int slot = ((a << 2) ^ (a & 7)) ^ cq;
        xs4[slot] = xr[i];
        ys4[slot] = yr[i];
    }
    __syncthreads();

    const int c4   = (threadIdx.x & 3) << 2;  // channel quad offset: 0,4,8,12
    const int dloc = threadIdx.x >> 2;        // 0..255, local output index
    float* __restrict__ orow = out + (size_t)n * (DIM * C);

    #pragma unroll
    for (int db = 0; db < DIM; db += TPB / 4) {   // 2 iterations
        const int d = db + dloc;
        const int s = start[d];
        const int e = start[d + 1];
        float ax = 0.f, ay = 0.f, az = 0.f, aw = 0.f;
        int p = s;
        if (p < e) {
            int4   pd = pdata[p];
            float4 xv = *reinterpret_cast<const float4*>(xs + (pd.x ^ c4));
            float4 yv = *reinterpret_cast<const float4*>(ys + (pd.y ^ c4));
            while (++p < e) {
                // issue next path's loads before consuming current
                const int4   pdn = pdata[p];
                const float4 xvn = *reinterpret_cast<const float4*>(xs + (pdn.x ^ c4));
                const float4 yvn = *reinterpret_cast<const float4*>(ys + (pdn.y ^ c4));
                const float sc = __int_as_float(pd.z);
                ax = fmaf(sc * xv.x, yv.x, ax);
                ay = fmaf(sc * xv.y, yv.y, ay);
                az = fmaf(sc * xv.z, yv.z, az);
                aw = fmaf(sc * xv.w, yv.w, aw);
                pd = pdn; xv = xvn; yv = yvn;
            }
            const float sc = __int_as_float(pd.z);
            ax = fmaf(sc * xv.x, yv.x, ax);
            ay = fmaf(sc * xv.y, yv.y, ay);
            az = fmaf(sc * xv.z, yv.z, az);
            aw = fmaf(sc * xv.w, yv.w, aw);
        }
        *reinterpret_cast<float4*>(orow + d * C + c4) = make_float4(ax, ay, az, aw);
    }
}

extern "C" void kernel_launch(void* const* d_in, const int* in_sizes, int n_in,
                              void* d_out, int out_size, void* d_ws, size_t ws_size,
                              hipStream_t stream) {
    const float* x     = (const float*)d_in[0];
    const float* y     = (const float*)d_in[1];
    const float* scale = (const float*)d_in[2];
    const int*   i1    = (const int*)d_in[3];
    const int*   i2    = (const int*)d_in[4];
    const int*   io    = (const int*)d_in[5];
    float* out = (float*)d_out;

    const int nnz = in_sizes[2];
    const int N   = in_sizes[0] / (DIM * C);

    int*  start = (int*)d_ws;                        // DIM+1 ints
    int4* pdata = (int4*)((char*)d_ws + 4096);       // NNZ int4s (64 KiB)

    const int setup_threads = (nnz > DIM + 1 ? nnz : DIM + 1);
    setup_kernel<<<(setup_threads + 255) / 256, 256, 0, stream>>>(
        io, i1, i2, scale, start, pdata, nnz);
    tp_lds_kernel<<<N, TPB, 0, stream>>>(x, y, start, pdata, out);
}